// Round 4
// baseline (64459.851 us; speedup 1.0000x reference)
//
#include <hip/hip_runtime.h>
#include <hip/hip_cooperative_groups.h>

namespace cg = cooperative_groups;

#define T_STEPS 256
// sizes: M=4 N=48 H1=4160 HID=2320 3HID=6960 H2=768 OUT=192 KGIN=52

// ---------- ws byte-offset layout ----------
#define O_HF0   0          // 2320 f32 (h state ping)
#define O_HF1   9280       // 2320 f32 (h state pong)
#define O_L2    18560      // 768 f32
#define O_V     21632      // 3072 f32
#define O_C     33920      // 4 f32
#define O_L1B   33952      // 4160 bf16
#define O_HB0   42272      // 2336 bf16 (incl 16 pad)
#define O_HB1   46944      // 2336 bf16
// legacy fp32-path offsets (float units)
#define WS_L1  0
#define WS_H0  4160
#define WS_H1  6480
#define WS_L2  8800
#define WS_V   9568
#define WS_C   12640
#define WS_XPR 12648
#define WS_INN 12656
#define WS_KG  12704
// bf16 weights
#define BW_BASE   65536
#define N_IH      28953600              // 6960*4160
#define N_HH      16147200              // 6960*2320
#define N_W2      1781760               // 768*2320
#define O_WIH     ((size_t)BW_BASE)
#define O_WHH     (O_WIH + (size_t)N_IH * 2)
#define O_W2      (O_WHH + (size_t)N_HH * 2)
#define BW_END    (O_W2 + (size_t)N_W2 * 2)          // 93,830,656 (64-aligned)
#define O_GI      BW_END                              // 6960 f32
#define O_GH      (O_GI + 27840)
#define WS_NEED   (O_GH + 27840 + 64)

typedef __attribute__((ext_vector_type(8))) short bf16x8;
typedef __attribute__((ext_vector_type(4))) float f32x4;

__device__ __forceinline__ float wred(float v) {
#pragma unroll
  for (int m = 32; m; m >>= 1) v += __shfl_xor(v, m, 64);
  return v;
}
__device__ __forceinline__ float dot4(float4 a, float4 b) {
  return a.x * b.x + a.y * b.y + a.z * b.z + a.w * b.w;
}
__device__ __forceinline__ float blo(unsigned u) {
  unsigned t = u << 16; return __builtin_bit_cast(float, t);
}
__device__ __forceinline__ float bhi(unsigned u) {
  unsigned t = u & 0xFFFF0000u; return __builtin_bit_cast(float, t);
}
__device__ __forceinline__ float dot8bb(uint4 w, uint4 x) {
  float s;
  s  = blo(w.x) * blo(x.x) + bhi(w.x) * bhi(x.x);
  s += blo(w.y) * blo(x.y) + bhi(w.y) * bhi(x.y);
  s += blo(w.z) * blo(x.z) + bhi(w.z) * bhi(x.z);
  s += blo(w.w) * blo(x.w) + bhi(w.w) * bhi(x.w);
  return s;
}
__device__ __forceinline__ unsigned short f2bf(float f) {  // RNE
  unsigned u = __builtin_bit_cast(unsigned, f);
  unsigned r = u + 0x7FFF + ((u >> 16) & 1);
  return (unsigned short)(r >> 16);
}

// ---------------- fp32 -> bf16 conversion ----------------
__global__ __launch_bounds__(256) void k_cvt(const float4* __restrict__ src,
                                             ushort4* __restrict__ dst, int n4) {
  int i = blockIdx.x * 256 + threadIdx.x, st = gridDim.x * 256;
  for (; i < n4; i += st) {
    float4 v = src[i];
    ushort4 o;
    o.x = f2bf(v.x); o.y = f2bf(v.y); o.z = f2bf(v.z); o.w = f2bf(v.w);
    dst[i] = o;
  }
}

// ================= MFMA cooperative kernel =================
__global__ __launch_bounds__(256, 4) void knet_m(
    const float* __restrict__ y_seq, const float* __restrict__ x0,
    const float* __restrict__ h0, const float* __restrict__ A,
    const float* __restrict__ Cm, const float* __restrict__ W1,
    const float* __restrict__ b1, const float* __restrict__ b_ih,
    const float* __restrict__ b_hh, const float* __restrict__ b2,
    const float* __restrict__ W3, const float* __restrict__ b3,
    float* __restrict__ out, char* __restrict__ wsb)
{
  cg::grid_group grid = cg::this_grid();
  const int tid = threadIdx.x, lane = tid & 63, wav = tid >> 6, bid = blockIdx.x;
  const int gt = bid * 256 + tid;
  const int NB = gridDim.x;

  const unsigned short* bwih = (const unsigned short*)(wsb + O_WIH);
  const unsigned short* bwhh = (const unsigned short*)(wsb + O_WHH);
  const unsigned short* bw2  = (const unsigned short*)(wsb + O_W2);
  float* gi   = (float*)(wsb + O_GI);
  float* gh   = (float*)(wsb + O_GH);
  float* vws  = (float*)(wsb + O_V);
  float* cws  = (float*)(wsb + O_C);
  float* l2ws = (float*)(wsb + O_L2);

  __shared__ __align__(16) uint4 s_x4[520];       // x staging (bf16): l1 / h
  __shared__ float s_part[4][16];
  __shared__ __align__(16) float s_kgin[52];
  __shared__ float s_innov[48];
  __shared__ float s_xpost[4], s_xprior[4], s_dx[4];
  __shared__ float s_sc2, s_sc4;

  for (int t = 0; t <= T_STEPS; ++t) {
    // ---------- P1a: x_post (= x_new of step t-1) ----------
    if (t == 0) {
      if (tid < 4) s_xpost[tid] = x0[tid];
    } else {
      const float4* vv  = (const float4*)(vws + wav * 768);
      const float4* l2v = (const float4*)l2ws;
      float acc = 0.f;
#pragma unroll 3
      for (int k = lane; k < 192; k += 64) acc += dot4(vv[k], l2v[k]);
      acc = wred(acc);
      if (lane == 0)
        s_xpost[wav] = s_xprior[wav] + (acc + cws[wav]) * 1e-4f;
    }
    __syncthreads();
    if (bid == 0 && t > 0 && tid < 4) out[tid * T_STEPS + (t - 1)] = s_xpost[tid];
    if (t == T_STEPS) return;

    // ---------- P1b: x_prior, innov, kg_in ----------
    if (tid < 4) {
      float xp = 0.f;
#pragma unroll
      for (int j = 0; j < 4; j++) xp += A[tid * 4 + j] * s_xpost[j];
      s_xprior[tid] = xp;
    }
    __syncthreads();
    if (tid < 48) {
      float yp = Cm[tid * 5 + 4];
#pragma unroll
      for (int j = 0; j < 4; j++) yp += Cm[tid * 5 + j] * s_xprior[j];
      s_innov[tid] = y_seq[tid * T_STEPS + t] - yp;
    }
    if (tid >= 64 && tid < 68) {
      int i = tid - 64;
      s_dx[i] = s_xpost[i] - s_xprior[i];
    }
    __syncthreads();
    if (tid == 0) {
      float s2 = 0.f;
      for (int r = 0; r < 48; r++) s2 += s_innov[r] * s_innov[r];
      s_sc2 = 1.0f / fmaxf(sqrtf(s2), 1e-12f);
      float s4 = 0.f;
      for (int i = 0; i < 4; i++) s4 += s_dx[i] * s_dx[i];
      s_sc4 = 1.0f / fmaxf(sqrtf(s4), 1e-12f);
    }
    __syncthreads();
    if (tid < 48) s_kgin[tid] = s_innov[tid] * s_sc2;
    else if (tid < 52) s_kgin[tid] = s_dx[tid - 48] * s_sc4;
    __syncthreads();

    // ---------- P1c: l1(bf16), v, c, (t0: hb init) ----------
    if (gt < 4160) {
      const float4* wr  = (const float4*)(W1 + (size_t)gt * 52);
      const float4* kg4 = (const float4*)s_kgin;
      float acc = b1[gt];
#pragma unroll
      for (int k = 0; k < 13; k++) acc += dot4(wr[k], kg4[k]);
      ((unsigned short*)(wsb + O_L1B))[gt] = f2bf(fmaxf(acc, 0.f));
    } else if (gt < 7232) {
      int idx = gt - 4160;
      int i = idx / 768, cc = idx - i * 768;
      const float* wcol = W3 + (size_t)(i * 48) * 768 + cc;
      float acc = 0.f;
#pragma unroll 8
      for (int j = 0; j < 48; j++) acc += s_innov[j] * wcol[(size_t)j * 768];
      vws[idx] = acc;
    } else if (gt < 7236) {
      int i = gt - 7232;
      float acc = 0.f;
      for (int j = 0; j < 48; j++) acc += s_innov[j] * b3[i * 48 + j];
      cws[i] = acc;
    }
    if (t == 0) {
      if (gt >= 7424 && gt < 9760) {
        int j = gt - 7424;
        ((unsigned short*)(wsb + O_HB0))[j] = (j < 2320) ? f2bf(h0[j]) : 0;
      }
      if (gt >= 9760 && gt < 9776)
        ((unsigned short*)(wsb + O_HB1))[2320 + (gt - 9760)] = 0;
    }
    grid.sync();  // S1

    // ---------- P2a: MFMA GEMV tiles (gi, gh) ----------
    for (int role = bid; role < 870; role += NB) {
      const int side = (role < 435) ? 0 : 1;
      const int r2 = side ? role - 435 : role;
      const int g = r2 / 145, jt = r2 - g * 145;
      if (side == 0) {
        const uint4* src = (const uint4*)(wsb + O_L1B);
        for (int i = tid; i < 520; i += 256) s_x4[i] = src[i];
      } else {
        const uint4* src = (const uint4*)(wsb + ((t & 1) ? O_HB1 : O_HB0));
        for (int i = tid; i < 292; i += 256) s_x4[i] = src[i];
      }
      __syncthreads();
      f32x4 acc = {0.f, 0.f, 0.f, 0.f};
      const int grow = g * 2320 + jt * 16 + (lane & 15);
      const uint4* xb = s_x4 + (lane >> 4);
      if (side == 0) {
        const uint4* ab = (const uint4*)(bwih + (size_t)grow * 4160) + (lane >> 4);
#pragma unroll 8
        for (int kt = wav; kt < 130; kt += 4)
          acc = __builtin_amdgcn_mfma_f32_16x16x32_bf16(
              __builtin_bit_cast(bf16x8, ab[kt * 4]),
              __builtin_bit_cast(bf16x8, xb[kt * 4]), acc, 0, 0, 0);
      } else {
        const uint4* ab = (const uint4*)(bwhh + (size_t)grow * 2320) + (lane >> 4);
#pragma unroll 8
        for (int kt = wav; kt < 73; kt += 4)
          acc = __builtin_amdgcn_mfma_f32_16x16x32_bf16(
              __builtin_bit_cast(bf16x8, ab[kt * 4]),
              __builtin_bit_cast(bf16x8, xb[kt * 4]), acc, 0, 0, 0);
      }
      if ((lane & 15) == 0) {
        int rb = (lane >> 4) * 4;
#pragma unroll
        for (int i = 0; i < 4; i++) s_part[wav][rb + i] = acc[i];
      }
      __syncthreads();
      if (tid < 16) {
        float s = s_part[0][tid] + s_part[1][tid] + s_part[2][tid] + s_part[3][tid];
        (side ? gh : gi)[g * 2320 + jt * 16 + tid] = s;
      }
      __syncthreads();
    }
    grid.sync();  // S2a

    // ---------- P2b: gate combine -> h_new ----------
    if (gt < 2320) {
      const int j = gt;
      float ir = gi[j] + b_ih[j];
      float iz = gi[2320 + j] + b_ih[2320 + j];
      float ig = gi[4640 + j] + b_ih[4640 + j];
      float hr = gh[j] + b_hh[j];
      float hz = gh[2320 + j] + b_hh[2320 + j];
      float hg = gh[4640 + j] + b_hh[4640 + j];
      float rr = 1.f / (1.f + expf(-(ir + hr)));
      float zz = 1.f / (1.f + expf(-(iz + hz)));
      float gg = tanhf(ig + rr * hg);
      float hold = (t == 0) ? h0[j] : ((const float*)(wsb + ((t & 1) ? O_HF1 : O_HF0)))[j];
      float hn = (1.f - zz) * gg + zz * hold;
      ((float*)(wsb + ((t & 1) ? O_HF0 : O_HF1)))[j] = hn;
      ((unsigned short*)(wsb + ((t & 1) ? O_HB0 : O_HB1)))[j] = f2bf(hn);
    }
    grid.sync();  // S2b

    // ---------- P3: l2 (bf16 VALU dot, conflict-free) ----------
    if (bid < 192) {
      const uint4* src = (const uint4*)(wsb + ((t & 1) ? O_HB0 : O_HB1));
      for (int i = tid; i < 292; i += 256) s_x4[i] = src[i];
      __syncthreads();
      const int task = bid * 4 + wav;
      if (task < 768) {
        const uint4* row = (const uint4*)(bw2 + (size_t)task * 2320);
        float acc = 0.f;
#pragma unroll 4
        for (int k = lane; k < 290; k += 64) acc += dot8bb(row[k], s_x4[k]);
        acc = wred(acc);
        if (lane == 0) l2ws[task] = fmaxf(acc + b2[task], 0.f);
      }
      __syncthreads();
    }
    grid.sync();  // S3
  }
}

// ================= cooperative fp32 kernel (fallback 1, proven) =================
__global__ __launch_bounds__(256, 2) void knet(
    const float* __restrict__ y_seq, const float* __restrict__ x0,
    const float* __restrict__ h0, const float* __restrict__ A,
    const float* __restrict__ Cm, const float* __restrict__ W1,
    const float* __restrict__ b1, const float* __restrict__ W_ih,
    const float* __restrict__ W_hh, const float* __restrict__ b_ih,
    const float* __restrict__ b_hh, const float* __restrict__ W2,
    const float* __restrict__ b2, const float* __restrict__ W3,
    const float* __restrict__ b3, float* __restrict__ out,
    float* __restrict__ ws)
{
  cg::grid_group grid = cg::this_grid();
  const int tid = threadIdx.x, lane = tid & 63, wav = tid >> 6, bid = blockIdx.x;
  const int gt = bid * 256 + tid, wave_g = bid * 4 + wav, NW = gridDim.x * 4;

  __shared__ __align__(16) float4 s_buf4[1040];
  __shared__ __align__(16) float4 s_h4[580];
  __shared__ __align__(16) float s_kgin[52];
  __shared__ float s_innov[48];
  __shared__ float s_xpost[4], s_xprior[4], s_dx[4];
  __shared__ float s_sc2, s_sc4;

  for (int t = 0; t <= T_STEPS; ++t) {
    if (t == 0) {
      if (tid < 4) s_xpost[tid] = x0[tid];
    } else {
      const float4* vv  = (const float4*)(ws + WS_V + wav * 768);
      const float4* l2v = (const float4*)(ws + WS_L2);
      float acc = 0.f;
      for (int k = lane; k < 192; k += 64) acc += dot4(vv[k], l2v[k]);
      acc = wred(acc);
      if (lane == 0)
        s_xpost[wav] = s_xprior[wav] + (acc + ws[WS_C + wav]) * 1e-4f;
    }
    __syncthreads();
    if (bid == 0 && t > 0 && tid < 4) out[tid * T_STEPS + (t - 1)] = s_xpost[tid];
    if (t == T_STEPS) return;

    if (tid < 4) {
      float xp = 0.f;
#pragma unroll
      for (int j = 0; j < 4; j++) xp += A[tid * 4 + j] * s_xpost[j];
      s_xprior[tid] = xp;
    }
    __syncthreads();
    if (tid < 48) {
      float yp = Cm[tid * 5 + 4];
#pragma unroll
      for (int j = 0; j < 4; j++) yp += Cm[tid * 5 + j] * s_xprior[j];
      s_innov[tid] = y_seq[tid * T_STEPS + t] - yp;
    }
    if (tid >= 64 && tid < 68) {
      int i = tid - 64;
      s_dx[i] = s_xpost[i] - s_xprior[i];
    }
    __syncthreads();
    if (tid == 0) {
      float s2 = 0.f;
      for (int r = 0; r < 48; r++) s2 += s_innov[r] * s_innov[r];
      s_sc2 = 1.0f / fmaxf(sqrtf(s2), 1e-12f);
      float s4 = 0.f;
      for (int i = 0; i < 4; i++) s4 += s_dx[i] * s_dx[i];
      s_sc4 = 1.0f / fmaxf(sqrtf(s4), 1e-12f);
    }
    __syncthreads();
    if (tid < 48) s_kgin[tid] = s_innov[tid] * s_sc2;
    else if (tid < 52) s_kgin[tid] = s_dx[tid - 48] * s_sc4;
    __syncthreads();

    if (gt < 4160) {
      const float4* wr  = (const float4*)(W1 + (size_t)gt * 52);
      const float4* kg4 = (const float4*)s_kgin;
      float acc = b1[gt];
#pragma unroll
      for (int k = 0; k < 13; k++) acc += dot4(wr[k], kg4[k]);
      ws[WS_L1 + gt] = fmaxf(acc, 0.f);
    }
    grid.sync();

    {
      const float* h_old = (t == 0) ? h0 : (ws + (((t & 1) == 0) ? WS_H0 : WS_H1));
      float* h_new = ws + (((t & 1) == 0) ? WS_H1 : WS_H0);
      const float4* l1g = (const float4*)(ws + WS_L1);
      for (int i = tid; i < 1040; i += 256) s_buf4[i] = l1g[i];
      const float4* hog = (const float4*)h_old;
      for (int i = tid; i < 580; i += 256) s_h4[i] = hog[i];
      __syncthreads();
      const float* s_h = (const float*)s_h4;

      for (int j = wave_g; j < 2320; j += NW) {
        const float4* r0 = (const float4*)(W_ih + (size_t)j * 4160);
        const float4* r1 = (const float4*)(W_ih + (size_t)(j + 2320) * 4160);
        const float4* r2 = (const float4*)(W_ih + (size_t)(j + 4640) * 4160);
        float a0 = 0.f, a1 = 0.f, a2 = 0.f;
#pragma unroll 4
        for (int k = lane; k < 1040; k += 64) {
          float4 x = s_buf4[k];
          a0 += dot4(r0[k], x); a1 += dot4(r1[k], x); a2 += dot4(r2[k], x);
        }
        const float4* q0 = (const float4*)(W_hh + (size_t)j * 2320);
        const float4* q1 = (const float4*)(W_hh + (size_t)(j + 2320) * 2320);
        const float4* q2 = (const float4*)(W_hh + (size_t)(j + 4640) * 2320);
        float c0 = 0.f, c1 = 0.f, c2 = 0.f;
#pragma unroll 4
        for (int k = lane; k < 580; k += 64) {
          float4 x = s_h4[k];
          c0 += dot4(q0[k], x); c1 += dot4(q1[k], x); c2 += dot4(q2[k], x);
        }
        a0 = wred(a0); a1 = wred(a1); a2 = wred(a2);
        c0 = wred(c0); c1 = wred(c1); c2 = wred(c2);
        if (lane == 0) {
          float ir = a0 + b_ih[j], iz = a1 + b_ih[j + 2320], ig = a2 + b_ih[j + 4640];
          float hr = c0 + b_hh[j], hz = c1 + b_hh[j + 2320], hg = c2 + b_hh[j + 4640];
          float rr = 1.f / (1.f + expf(-(ir + hr)));
          float zz = 1.f / (1.f + expf(-(iz + hz)));
          float gg = tanhf(ig + rr * hg);
          h_new[j] = (1.f - zz) * gg + zz * s_h[j];
        }
      }
    }
    grid.sync();

    {
      const float* h_new = ws + (((t & 1) == 0) ? WS_H1 : WS_H0);
      const float4* hv = (const float4*)h_new;
      for (int i = tid; i < 580; i += 256) s_buf4[i] = hv[i];
      __syncthreads();

      if (gt < 3072) {
        int i = gt / 768, cc = gt - i * 768;
        const float* wcol = W3 + (size_t)(i * 48) * 768 + cc;
        float acc = 0.f;
#pragma unroll 8
        for (int j = 0; j < 48; j++) acc += s_innov[j] * wcol[(size_t)j * 768];
        ws[WS_V + gt] = acc;
      } else if (gt < 3076) {
        int i = gt - 3072;
        float acc = 0.f;
        for (int j = 0; j < 48; j++) acc += s_innov[j] * b3[i * 48 + j];
        ws[WS_C + i] = acc;
      }

      for (int task = wave_g; task < 768; task += NW) {
        const float4* row = (const float4*)(W2 + (size_t)task * 2320);
        float acc = 0.f;
#pragma unroll 4
        for (int k = lane; k < 580; k += 64) acc += dot4(row[k], s_buf4[k]);
        acc = wred(acc);
        if (lane == 0) ws[WS_L2 + task] = fmaxf(acc + b2[task], 0.f);
      }
    }
    grid.sync();
  }
}

extern "C" void kernel_launch(void* const* d_in, const int* in_sizes, int n_in,
                              void* d_out, int out_size, void* d_ws, size_t ws_size,
                              hipStream_t stream) {
  const float* y_seq = (const float*)d_in[0];
  const float* x0    = (const float*)d_in[1];
  const float* h0    = (const float*)d_in[2];
  const float* A     = (const float*)d_in[3];
  const float* Cm    = (const float*)d_in[4];
  const float* W1    = (const float*)d_in[5];
  const float* b1    = (const float*)d_in[6];
  const float* W_ih  = (const float*)d_in[7];
  const float* W_hh  = (const float*)d_in[8];
  const float* b_ih  = (const float*)d_in[9];
  const float* b_hh  = (const float*)d_in[10];
  const float* W2    = (const float*)d_in[11];
  const float* b2    = (const float*)d_in[12];
  const float* W3    = (const float*)d_in[13];
  const float* b3    = (const float*)d_in[14];
  float* out = (float*)d_out;
  float* ws  = (float*)d_ws;
  char* wsb  = (char*)d_ws;

  if (ws_size >= WS_NEED) {
    unsigned short* bwih = (unsigned short*)(wsb + O_WIH);
    unsigned short* bwhh = (unsigned short*)(wsb + O_WHH);
    unsigned short* bw2  = (unsigned short*)(wsb + O_W2);
    k_cvt<<<1024, 256, 0, stream>>>((const float4*)W_ih, (ushort4*)bwih, N_IH / 4);
    k_cvt<<<1024, 256, 0, stream>>>((const float4*)W_hh, (ushort4*)bwhh, N_HH / 4);
    k_cvt<<<512, 256, 0, stream>>>((const float4*)W2, (ushort4*)bw2, N_W2 / 4);

    int nb = 0;
    hipError_t oe = hipOccupancyMaxActiveBlocksPerMultiprocessor(
        &nb, (const void*)knet_m, 256, 0);
    int bpc = (oe == hipSuccess && nb >= 1) ? (nb > 4 ? 4 : nb) : 1;

    void* args[] = { &y_seq, &x0, &h0, &A, &Cm, &W1, &b1, &b_ih, &b_hh,
                     &b2, &W3, &b3, &out, &wsb };
    hipError_t err = hipLaunchCooperativeKernel(
        reinterpret_cast<void*>(knet_m), dim3(256 * bpc), dim3(256), args, 0, stream);
    if (err == hipSuccess) return;
  }

  {
    int nb = 0;
    hipError_t oe = hipOccupancyMaxActiveBlocksPerMultiprocessor(
        &nb, (const void*)knet, 256, 0);
    int bpc = (oe == hipSuccess && nb >= 1) ? (nb > 3 ? 3 : nb) : 1;
    void* args[] = { &y_seq, &x0, &h0, &A, &Cm, &W1, &b1, &W_ih, &W_hh,
                     &b_ih, &b_hh, &W2, &b2, &W3, &b3, &out, &ws };
    hipLaunchCooperativeKernel(
        reinterpret_cast<void*>(knet), dim3(256 * bpc), dim3(256), args, 0, stream);
  }
}

// Round 5
// 35697.260 us; speedup vs baseline: 1.8057x; 1.8057x over previous
//
#include <hip/hip_runtime.h>
#include <hip/hip_cooperative_groups.h>

namespace cg = cooperative_groups;

#define T_STEPS 256
// sizes: M=4 N=48 H1=4160 HID=2320 3HID=6960 H2=768 OUT=192 KGIN=52

// ---------------- ws byte-offset layout (new path) ----------------
#define O_BAR   0                  // 10 u32 barrier state (memset each launch)
#define O_ZP    256                // 96*4 f32 z-partials
#define O_HF    2048               // 2 x 2320 f32 (h state, parity)
#define HF_STR  9280
#define O_HB    20608              // 2 x 2336 bf16 (h state bf16, parity)
#define HB_STR  4672
#define O_GI    30208              // 6960 f32
#define O_GH    58048              // 6960 f32
#define O_WIH   86016              // 6960*4160 bf16
#define O_WHH   57993216           // 6960*2320 bf16
#define O_W2B   90287616           // 768*2320 bf16
#define NEED_MIN 93851136
#define O_W1P   93851136           // 4160*56 bf16 (padded W1)
#define NEED_FULL 94317056

#define N_IH  28953600
#define N_HH  16147200
#define N_W2  1781760

// legacy fp32-path offsets (float units) for fallback kernel
#define WS_L1  0
#define WS_H0  4160
#define WS_H1  6480
#define WS_L2  8800
#define WS_V   9568
#define WS_C   12640

typedef __attribute__((ext_vector_type(8))) short bf16x8;
typedef __attribute__((ext_vector_type(4))) float f32x4;

__device__ __forceinline__ float wred(float v) {
#pragma unroll
  for (int m = 32; m; m >>= 1) v += __shfl_xor(v, m, 64);
  return v;
}
__device__ __forceinline__ float dot4(float4 a, float4 b) {
  return a.x * b.x + a.y * b.y + a.z * b.z + a.w * b.w;
}
__device__ __forceinline__ float blo(unsigned u) {
  unsigned t = u << 16; return __builtin_bit_cast(float, t);
}
__device__ __forceinline__ float bhi(unsigned u) {
  unsigned t = u & 0xFFFF0000u; return __builtin_bit_cast(float, t);
}
__device__ __forceinline__ float dot8bb(uint4 w, uint4 x) {
  float s;
  s  = blo(w.x) * blo(x.x) + bhi(w.x) * bhi(x.x);
  s += blo(w.y) * blo(x.y) + bhi(w.y) * bhi(x.y);
  s += blo(w.z) * blo(x.z) + bhi(w.z) * bhi(x.z);
  s += blo(w.w) * blo(x.w) + bhi(w.w) * bhi(x.w);
  return s;
}
__device__ __forceinline__ unsigned short f2bf(float f) {  // RNE
  unsigned u = __builtin_bit_cast(unsigned, f);
  unsigned r = u + 0x7FFF + ((u >> 16) & 1);
  return (unsigned short)(r >> 16);
}

// ---------- two-level grid barrier (8 groups of 32 + leader + epoch) ----------
__device__ __forceinline__ void gbar(unsigned* bar, int bid, unsigned target) {
  __syncthreads();
  if (threadIdx.x == 0) {
    __threadfence();  // release our writes device-wide
    unsigned* grp   = bar + (bid & 7);
    unsigned* lead  = bar + 8;
    unsigned* epoch = bar + 9;
    unsigned old = __hip_atomic_fetch_add(grp, 1u, __ATOMIC_ACQ_REL, __HIP_MEMORY_SCOPE_AGENT);
    if (old == 31u) {
      __hip_atomic_store(grp, 0u, __ATOMIC_RELAXED, __HIP_MEMORY_SCOPE_AGENT);
      unsigned lo = __hip_atomic_fetch_add(lead, 1u, __ATOMIC_ACQ_REL, __HIP_MEMORY_SCOPE_AGENT);
      if (lo == 7u) {
        __hip_atomic_store(lead, 0u, __ATOMIC_RELAXED, __HIP_MEMORY_SCOPE_AGENT);
        __hip_atomic_store(epoch, target, __ATOMIC_RELEASE, __HIP_MEMORY_SCOPE_AGENT);
      } else {
        while (__hip_atomic_load(epoch, __ATOMIC_ACQUIRE, __HIP_MEMORY_SCOPE_AGENT) < target)
          __builtin_amdgcn_s_sleep(1);
      }
    } else {
      while (__hip_atomic_load(epoch, __ATOMIC_ACQUIRE, __HIP_MEMORY_SCOPE_AGENT) < target)
        __builtin_amdgcn_s_sleep(1);
    }
    __threadfence();  // acquire remote writes
  }
  __syncthreads();
}

// ---------------- pre-pass conversion kernels ----------------
__global__ __launch_bounds__(256) void k_cvt(const float4* __restrict__ src,
                                             ushort4* __restrict__ dst, int n4) {
  int i = blockIdx.x * 256 + threadIdx.x, st = gridDim.x * 256;
  for (; i < n4; i += st) {
    float4 v = src[i];
    ushort4 o;
    o.x = f2bf(v.x); o.y = f2bf(v.y); o.z = f2bf(v.z); o.w = f2bf(v.w);
    dst[i] = o;
  }
}
__global__ __launch_bounds__(256) void k_cvtw1(const float* __restrict__ W1,
                                               unsigned short* __restrict__ dst) {
  int i = blockIdx.x * 256 + threadIdx.x;           // over 4160*56
  if (i < 4160 * 56) {
    int r = i / 56, c = i - r * 56;
    dst[i] = (c < 52) ? f2bf(W1[r * 52 + c]) : (unsigned short)0;
  }
}
__global__ __launch_bounds__(256) void k_h0(const float* __restrict__ h0,
                                            unsigned short* __restrict__ hb0,
                                            unsigned short* __restrict__ hb1) {
  int j = blockIdx.x * 256 + threadIdx.x;
  if (j < 2336) {
    hb1[j] = (j < 2320) ? f2bf(h0[j]) : (unsigned short)0;
    if (j >= 2320) hb0[j] = 0;
  }
}

// ================= main 2-sync cooperative kernel =================
__global__ __launch_bounds__(1024, 4) void knet2(
    const float* __restrict__ y_seq, const float* __restrict__ x0,
    const float* __restrict__ h0, const float* __restrict__ A,
    const float* __restrict__ Cm, const float* __restrict__ W1,
    const float* __restrict__ b1, const float* __restrict__ b_ih,
    const float* __restrict__ b_hh, const float* __restrict__ b2,
    const float* __restrict__ W3, const float* __restrict__ b3,
    float* __restrict__ out, char* __restrict__ wsb, int use_w1p)
{
  const int tid  = threadIdx.x;
  const int lane = tid & 63;
  const int wav  = tid >> 6;
  const int bid  = blockIdx.x;

  unsigned* bar = (unsigned*)(wsb + O_BAR);
  float* zp  = (float*)(wsb + O_ZP);
  float* gi  = (float*)(wsb + O_GI);
  float* gh  = (float*)(wsb + O_GH);
  const unsigned short* bwih = (const unsigned short*)(wsb + O_WIH);
  const unsigned short* bwhh = (const unsigned short*)(wsb + O_WHH);
  const unsigned short* bw2  = (const unsigned short*)(wsb + O_W2B);
  const uint4* w1p = (const uint4*)(wsb + O_W1P);

  __shared__ __align__(16) uint4 s_l1u[520];     // l1 bf16 (B')
  __shared__ __align__(16) uint4 s_h4u[292];     // h bf16 (B' MFMA operand)
  __shared__ __align__(16) unsigned short s_h2[2336];  // h_new bf16 (C)
  __shared__ float s_part[4][4][16];
  __shared__ __align__(16) unsigned short s_kgb[64];
  __shared__ __align__(16) float s_kgf[52];
  __shared__ float s_innov[48];
  __shared__ float s_a[192];
  __shared__ float s_l2loc[8];
  __shared__ float s_xpost[4], s_xprior[4], s_dx[4];
  __shared__ float s_sc2, s_sc4;

  unsigned ep = 0;

  for (int t = 0; t <= T_STEPS; ++t) {
    // ======== B' prologue: x_post(t) from z-partials(t-1) [all blocks, redundant] ========
    if (t == 0) {
      if (tid < 4) s_xpost[tid] = x0[tid];
    } else {
      if (tid < 4) {
        float z = 0.f;
        for (int p = 0; p < 96; ++p) z += zp[p * 4 + tid];
        float cb = 0.f;
        for (int j = 0; j < 48; ++j) cb += s_innov[j] * b3[tid * 48 + j];
        float xn = s_xprior[tid] + (z + cb) * 1e-4f;
        s_xpost[tid] = xn;
        if (bid == 0) out[tid * T_STEPS + (t - 1)] = xn;
      }
    }
    __syncthreads();
    if (t == T_STEPS) return;

    // ======== B' small math: x_prior, innov, kg_in ========
    if (tid < 4) {
      float xpr = 0.f;
#pragma unroll
      for (int j = 0; j < 4; j++) xpr += A[tid * 4 + j] * s_xpost[j];
      s_xprior[tid] = xpr;
    }
    __syncthreads();
    if (tid < 48) {
      float yp = Cm[tid * 5 + 4];
#pragma unroll
      for (int j = 0; j < 4; j++) yp += Cm[tid * 5 + j] * s_xprior[j];
      s_innov[tid] = y_seq[tid * T_STEPS + t] - yp;
    }
    if (tid >= 64 && tid < 68) {
      int i = tid - 64;
      s_dx[i] = s_xpost[i] - s_xprior[i];
    }
    __syncthreads();
    if (tid == 0) {
      float s2 = 0.f;
      for (int r = 0; r < 48; r++) s2 += s_innov[r] * s_innov[r];
      s_sc2 = 1.0f / fmaxf(sqrtf(s2), 1e-12f);
      float s4 = 0.f;
      for (int i = 0; i < 4; i++) s4 += s_dx[i] * s_dx[i];
      s_sc4 = 1.0f / fmaxf(sqrtf(s4), 1e-12f);
    }
    __syncthreads();
    if (tid < 64) {
      float v = (tid < 48) ? s_innov[tid] * s_sc2
              : (tid < 52) ? s_dx[tid - 48] * s_sc4 : 0.f;
      s_kgb[tid] = f2bf(v);
      if (tid < 52) s_kgf[tid] = v;
    }
    // stage h(t-1) bf16 into LDS
    {
      const uint4* hbg = (const uint4*)(wsb + O_HB + ((t + 1) & 1) * HB_STR);
      if (tid < 292) s_h4u[tid] = hbg[tid];
    }
    __syncthreads();

    // ======== B' l1 = relu(W1 @ kg + b1), redundant per block ========
    if (use_w1p) {
      const uint4* kg4 = (const uint4*)s_kgb;
      for (int r = tid; r < 4160; r += 1024) {
        const uint4* wr = w1p + (size_t)r * 7;
        float acc = b1[r];
#pragma unroll
        for (int c = 0; c < 7; c++) acc += dot8bb(wr[c], kg4[c]);
        ((unsigned short*)s_l1u)[r] = f2bf(fmaxf(acc, 0.f));
      }
    } else {
      const float4* kg4 = (const float4*)s_kgf;
      for (int r = tid; r < 4160; r += 1024) {
        const float4* wr = (const float4*)(W1 + (size_t)r * 52);
        float acc = b1[r];
#pragma unroll
        for (int c = 0; c < 13; c++) acc += dot4(wr[c], kg4[c]);
        ((unsigned short*)s_l1u)[r] = f2bf(fmaxf(acc, 0.f));
      }
    }
    __syncthreads();

    // ======== B' GRU GEMV via MFMA, 8-deep prefetch ========
    {
      const int q  = wav >> 2;        // job slot 0..3
      const int kw = wav & 3;         // k-split
      const int job = bid + 256 * q;
      if (job < 870) {
        const int side = (job < 435) ? 0 : 1;
        const int rt   = side ? (job - 435) : job;
        const int row  = rt * 16 + (lane & 15);
        const int xoff = lane >> 4;
        const uint4* xs;
        const uint4* wp;
        int kbeg, kend;
        if (side == 0) {
          xs = s_l1u;
          wp = (const uint4*)(bwih + (size_t)row * 4160) + xoff;
          kbeg = kw * 33; kend = kbeg + 33; if (kend > 130) kend = 130;
        } else {
          xs = s_h4u;
          wp = (const uint4*)(bwhh + (size_t)row * 2320) + xoff;
          kbeg = kw * 19; kend = kbeg + 19; if (kend > 73) kend = 73;
        }
        f32x4 acc = {0.f, 0.f, 0.f, 0.f};
        uint4 b0 = wp[(size_t)(kbeg + 0) * 4];
        uint4 b1r = wp[(size_t)(kbeg + 1) * 4];
        uint4 b2r = wp[(size_t)(kbeg + 2) * 4];
        uint4 b3r = wp[(size_t)(kbeg + 3) * 4];
        uint4 b4 = wp[(size_t)(kbeg + 4) * 4];
        uint4 b5 = wp[(size_t)(kbeg + 5) * 4];
        uint4 b6 = wp[(size_t)(kbeg + 6) * 4];
        uint4 b7 = wp[(size_t)(kbeg + 7) * 4];
        int kt = kbeg;
#define GSTEP(P, B) { acc = __builtin_amdgcn_mfma_f32_16x16x32_bf16( \
            __builtin_bit_cast(bf16x8, B), \
            __builtin_bit_cast(bf16x8, xs[(kt + P) * 4 + xoff]), acc, 0, 0, 0); \
            B = wp[(size_t)(kt + 8 + P) * 4]; }
        while (kt + 8 <= kend) {
          GSTEP(0, b0) GSTEP(1, b1r) GSTEP(2, b2r) GSTEP(3, b3r)
          GSTEP(4, b4) GSTEP(5, b5) GSTEP(6, b6) GSTEP(7, b7)
          kt += 8;
        }
#undef GSTEP
#define TSTEP(P, B) if (kt + P < kend) acc = __builtin_amdgcn_mfma_f32_16x16x32_bf16( \
            __builtin_bit_cast(bf16x8, B), \
            __builtin_bit_cast(bf16x8, xs[(kt + P) * 4 + xoff]), acc, 0, 0, 0);
        TSTEP(0, b0) TSTEP(1, b1r) TSTEP(2, b2r) TSTEP(3, b3r)
        TSTEP(4, b4) TSTEP(5, b5) TSTEP(6, b6) TSTEP(7, b7)
#undef TSTEP
        if ((lane & 15) == 0) {
          int rb = (lane >> 4) * 4;
#pragma unroll
          for (int i = 0; i < 4; i++) s_part[q][kw][rb + i] = acc[i];
        }
      }
    }
    __syncthreads();
    if (tid < 64) {
      int q = tid >> 4, r = tid & 15;
      int job = bid + 256 * q;
      if (job < 870) {
        float s = s_part[q][0][r] + s_part[q][1][r] + s_part[q][2][r] + s_part[q][3][r];
        if (job < 435) gi[job * 16 + r] = s;
        else gh[(job - 435) * 16 + r] = s;
      }
    }
    ++ep; gbar(bar, bid, ep);   // -------- SYNC 1: gi/gh ready --------

    // ======== C: gates (redundant on 96 blocks), l2, z-partials ========
    if (bid < 96) {
      float* hf_out = (float*)(wsb + O_HF + (t & 1) * HF_STR);
      unsigned short* hb_out = (unsigned short*)(wsb + O_HB + (t & 1) * HB_STR);
      const float* hf_old = (const float*)(wsb + O_HF + ((t + 1) & 1) * HF_STR);
      for (int j = tid; j < 2320; j += 1024) {
        float ir = gi[j] + b_ih[j];
        float iz = gi[2320 + j] + b_ih[2320 + j];
        float ig = gi[4640 + j] + b_ih[4640 + j];
        float hr = gh[j] + b_hh[j];
        float hz = gh[2320 + j] + b_hh[2320 + j];
        float hg = gh[4640 + j] + b_hh[4640 + j];
        float rr = 1.f / (1.f + expf(-(ir + hr)));
        float zz = 1.f / (1.f + expf(-(iz + hz)));
        float gg = tanhf(ig + rr * hg);
        float hold = (t == 0) ? h0[j] : hf_old[j];
        float hn = (1.f - zz) * gg + zz * hold;
        s_h2[j] = f2bf(hn);
        if (bid == 0) { hf_out[j] = hn; hb_out[j] = f2bf(hn); }
      }
      __syncthreads();
      // l2 rows (8 per block), bf16 VALU dot
      if (wav < 8) {
        const int row = bid * 8 + wav;
        const uint4* wr = (const uint4*)(bw2 + (size_t)row * 2320);
        const uint4* hx = (const uint4*)s_h2;
        float acc = 0.f;
        for (int k = lane; k < 290; k += 64) acc += dot8bb(wr[k], hx[k]);
        acc = wred(acc);
        if (lane == 0) s_l2loc[wav] = fmaxf(acc + b2[row], 0.f);
      }
      __syncthreads();
      // z-partials: a_{i,j} = sum_r W3[i*48+j][bid*8+r] * l2loc[r];  z_i = sum_j innov_j a_{i,j}
      if (tid < 192) {
        const float* w3r = W3 + (size_t)tid * 768 + bid * 8;
        float a = 0.f;
#pragma unroll
        for (int r = 0; r < 8; r++) a += w3r[r] * s_l2loc[r];
        s_a[tid] = a * s_innov[tid % 48];
      }
      __syncthreads();
      if (tid < 4) {
        float zv = 0.f;
        for (int j = 0; j < 48; j++) zv += s_a[tid * 48 + j];
        zp[bid * 4 + tid] = zv;
      }
    }
    ++ep; gbar(bar, bid, ep);   // -------- SYNC 2: h/l2/z ready --------
  }
}

// ================= cooperative fp32 kernel (proven fallback) =================
__global__ __launch_bounds__(256, 2) void knet(
    const float* __restrict__ y_seq, const float* __restrict__ x0,
    const float* __restrict__ h0, const float* __restrict__ A,
    const float* __restrict__ Cm, const float* __restrict__ W1,
    const float* __restrict__ b1, const float* __restrict__ W_ih,
    const float* __restrict__ W_hh, const float* __restrict__ b_ih,
    const float* __restrict__ b_hh, const float* __restrict__ W2,
    const float* __restrict__ b2, const float* __restrict__ W3,
    const float* __restrict__ b3, float* __restrict__ out,
    float* __restrict__ ws)
{
  cg::grid_group grid = cg::this_grid();
  const int tid = threadIdx.x, lane = tid & 63, wav = tid >> 6, bid = blockIdx.x;
  const int gt = bid * 256 + tid, wave_g = bid * 4 + wav, NW = gridDim.x * 4;

  __shared__ __align__(16) float4 s_buf4[1040];
  __shared__ __align__(16) float4 s_h4[580];
  __shared__ __align__(16) float s_kgin[52];
  __shared__ float s_innov[48];
  __shared__ float s_xpost[4], s_xprior[4], s_dx[4];
  __shared__ float s_sc2, s_sc4;

  for (int t = 0; t <= T_STEPS; ++t) {
    if (t == 0) {
      if (tid < 4) s_xpost[tid] = x0[tid];
    } else {
      const float4* vv  = (const float4*)(ws + WS_V + wav * 768);
      const float4* l2v = (const float4*)(ws + WS_L2);
      float acc = 0.f;
      for (int k = lane; k < 192; k += 64) acc += dot4(vv[k], l2v[k]);
      acc = wred(acc);
      if (lane == 0)
        s_xpost[wav] = s_xprior[wav] + (acc + ws[WS_C + wav]) * 1e-4f;
    }
    __syncthreads();
    if (bid == 0 && t > 0 && tid < 4) out[tid * T_STEPS + (t - 1)] = s_xpost[tid];
    if (t == T_STEPS) return;

    if (tid < 4) {
      float xp = 0.f;
#pragma unroll
      for (int j = 0; j < 4; j++) xp += A[tid * 4 + j] * s_xpost[j];
      s_xprior[tid] = xp;
    }
    __syncthreads();
    if (tid < 48) {
      float yp = Cm[tid * 5 + 4];
#pragma unroll
      for (int j = 0; j < 4; j++) yp += Cm[tid * 5 + j] * s_xprior[j];
      s_innov[tid] = y_seq[tid * T_STEPS + t] - yp;
    }
    if (tid >= 64 && tid < 68) {
      int i = tid - 64;
      s_dx[i] = s_xpost[i] - s_xprior[i];
    }
    __syncthreads();
    if (tid == 0) {
      float s2 = 0.f;
      for (int r = 0; r < 48; r++) s2 += s_innov[r] * s_innov[r];
      s_sc2 = 1.0f / fmaxf(sqrtf(s2), 1e-12f);
      float s4 = 0.f;
      for (int i = 0; i < 4; i++) s4 += s_dx[i] * s_dx[i];
      s_sc4 = 1.0f / fmaxf(sqrtf(s4), 1e-12f);
    }
    __syncthreads();
    if (tid < 48) s_kgin[tid] = s_innov[tid] * s_sc2;
    else if (tid < 52) s_kgin[tid] = s_dx[tid - 48] * s_sc4;
    __syncthreads();

    if (gt < 4160) {
      const float4* wr  = (const float4*)(W1 + (size_t)gt * 52);
      const float4* kg4 = (const float4*)s_kgin;
      float acc = b1[gt];
#pragma unroll
      for (int k = 0; k < 13; k++) acc += dot4(wr[k], kg4[k]);
      ws[WS_L1 + gt] = fmaxf(acc, 0.f);
    }
    grid.sync();

    {
      const float* h_old = (t == 0) ? h0 : (ws + (((t & 1) == 0) ? WS_H0 : WS_H1));
      float* h_new = ws + (((t & 1) == 0) ? WS_H1 : WS_H0);
      const float4* l1g = (const float4*)(ws + WS_L1);
      for (int i = tid; i < 1040; i += 256) s_buf4[i] = l1g[i];
      const float4* hog = (const float4*)h_old;
      for (int i = tid; i < 580; i += 256) s_h4[i] = hog[i];
      __syncthreads();
      const float* s_h = (const float*)s_h4;

      for (int j = wave_g; j < 2320; j += NW) {
        const float4* r0 = (const float4*)(W_ih + (size_t)j * 4160);
        const float4* r1 = (const float4*)(W_ih + (size_t)(j + 2320) * 4160);
        const float4* r2 = (const float4*)(W_ih + (size_t)(j + 4640) * 4160);
        float a0 = 0.f, a1 = 0.f, a2 = 0.f;
#pragma unroll 4
        for (int k = lane; k < 1040; k += 64) {
          float4 x = s_buf4[k];
          a0 += dot4(r0[k], x); a1 += dot4(r1[k], x); a2 += dot4(r2[k], x);
        }
        const float4* q0 = (const float4*)(W_hh + (size_t)j * 2320);
        const float4* q1 = (const float4*)(W_hh + (size_t)(j + 2320) * 2320);
        const float4* q2 = (const float4*)(W_hh + (size_t)(j + 4640) * 2320);
        float c0 = 0.f, c1 = 0.f, c2 = 0.f;
#pragma unroll 4
        for (int k = lane; k < 580; k += 64) {
          float4 x = s_h4[k];
          c0 += dot4(q0[k], x); c1 += dot4(q1[k], x); c2 += dot4(q2[k], x);
        }
        a0 = wred(a0); a1 = wred(a1); a2 = wred(a2);
        c0 = wred(c0); c1 = wred(c1); c2 = wred(c2);
        if (lane == 0) {
          float ir = a0 + b_ih[j], iz = a1 + b_ih[j + 2320], ig = a2 + b_ih[j + 4640];
          float hr = c0 + b_hh[j], hz = c1 + b_hh[j + 2320], hg = c2 + b_hh[j + 4640];
          float rr = 1.f / (1.f + expf(-(ir + hr)));
          float zz = 1.f / (1.f + expf(-(iz + hz)));
          float gg = tanhf(ig + rr * hg);
          h_new[j] = (1.f - zz) * gg + zz * s_h[j];
        }
      }
    }
    grid.sync();

    {
      const float* h_new = ws + (((t & 1) == 0) ? WS_H1 : WS_H0);
      const float4* hv = (const float4*)h_new;
      for (int i = tid; i < 580; i += 256) s_buf4[i] = hv[i];
      __syncthreads();

      if (gt < 3072) {
        int i = gt / 768, cc = gt - i * 768;
        const float* wcol = W3 + (size_t)(i * 48) * 768 + cc;
        float acc = 0.f;
#pragma unroll 8
        for (int j = 0; j < 48; j++) acc += s_innov[j] * wcol[(size_t)j * 768];
        ws[WS_V + gt] = acc;
      } else if (gt < 3076) {
        int i = gt - 3072;
        float acc = 0.f;
        for (int j = 0; j < 48; j++) acc += s_innov[j] * b3[i * 48 + j];
        ws[WS_C + i] = acc;
      }

      for (int task = wave_g; task < 768; task += NW) {
        const float4* row = (const float4*)(W2 + (size_t)task * 2320);
        float acc = 0.f;
#pragma unroll 4
        for (int k = lane; k < 580; k += 64) acc += dot4(row[k], s_buf4[k]);
        acc = wred(acc);
        if (lane == 0) ws[WS_L2 + task] = fmaxf(acc + b2[task], 0.f);
      }
    }
    grid.sync();
  }
}

extern "C" void kernel_launch(void* const* d_in, const int* in_sizes, int n_in,
                              void* d_out, int out_size, void* d_ws, size_t ws_size,
                              hipStream_t stream) {
  const float* y_seq = (const float*)d_in[0];
  const float* x0    = (const float*)d_in[1];
  const float* h0    = (const float*)d_in[2];
  const float* A     = (const float*)d_in[3];
  const float* Cm    = (const float*)d_in[4];
  const float* W1    = (const float*)d_in[5];
  const float* b1    = (const float*)d_in[6];
  const float* W_ih  = (const float*)d_in[7];
  const float* W_hh  = (const float*)d_in[8];
  const float* b_ih  = (const float*)d_in[9];
  const float* b_hh  = (const float*)d_in[10];
  const float* W2    = (const float*)d_in[11];
  const float* b2    = (const float*)d_in[12];
  const float* W3    = (const float*)d_in[13];
  const float* b3    = (const float*)d_in[14];
  float* out = (float*)d_out;
  float* ws  = (float*)d_ws;
  char* wsb  = (char*)d_ws;

  if (ws_size >= NEED_MIN) {
    int use_w1p = (ws_size >= NEED_FULL) ? 1 : 0;
    hipMemsetAsync(wsb + O_BAR, 0, 256, stream);
    k_cvt<<<1024, 256, 0, stream>>>((const float4*)W_ih,
                                    (ushort4*)(wsb + O_WIH), N_IH / 4);
    k_cvt<<<1024, 256, 0, stream>>>((const float4*)W_hh,
                                    (ushort4*)(wsb + O_WHH), N_HH / 4);
    k_cvt<<<512, 256, 0, stream>>>((const float4*)W2,
                                   (ushort4*)(wsb + O_W2B), N_W2 / 4);
    if (use_w1p)
      k_cvtw1<<<(4160 * 56 + 255) / 256, 256, 0, stream>>>(
          W1, (unsigned short*)(wsb + O_W1P));
    k_h0<<<10, 256, 0, stream>>>(h0, (unsigned short*)(wsb + O_HB),
                                 (unsigned short*)(wsb + O_HB + HB_STR));

    void* args[] = { &y_seq, &x0, &h0, &A, &Cm, &W1, &b1, &b_ih, &b_hh,
                     &b2, &W3, &b3, &out, &wsb, &use_w1p };
    hipError_t err = hipLaunchCooperativeKernel(
        reinterpret_cast<void*>(knet2), dim3(256), dim3(1024), args, 0, stream);
    if (err == hipSuccess) return;
  }

  {
    int nb = 0;
    hipError_t oe = hipOccupancyMaxActiveBlocksPerMultiprocessor(
        &nb, (const void*)knet, 256, 0);
    int bpc = (oe == hipSuccess && nb >= 1) ? (nb > 1 ? 1 : nb) : 1;
    void* args[] = { &y_seq, &x0, &h0, &A, &Cm, &W1, &b1, &W_ih, &W_hh,
                     &b_ih, &b_hh, &W2, &b2, &W3, &b3, &out, &ws };
    hipLaunchCooperativeKernel(
        reinterpret_cast<void*>(knet), dim3(256 * bpc), dim3(256), args, 0, stream);
  }
}

// Round 6
// 18063.351 us; speedup vs baseline: 3.5685x; 1.9762x over previous
//
#include <hip/hip_runtime.h>
#include <hip/hip_cooperative_groups.h>

namespace cg = cooperative_groups;

#define T_STEPS 256
// sizes: M=4 N=48 H1=4160 HID=2320 3HID=6960 H2=768 OUT=192 KGIN=52

// ---------------- ws byte-offset layout ----------------
#define O_BAR   0                  // 10 u32 barrier state (memset each launch)
#define O_ZP    256                // 96*4 f32 z-partials
#define O_HF    2048               // 2 x 2320 f32 (h state, parity)
#define HF_STR  9280
#define O_HB    20608              // 2 x 2336 bf16 (h state bf16, parity)
#define HB_STR  4672
#define O_GI    30208              // 6960 f32
#define O_GH    58048              // 6960 f32
#define O_WIH   86016              // 6960*4160 bf16
#define O_WHH   57993216           // 6960*2320 bf16
#define O_W2B   90287616           // 768*2320 bf16
#define NEED_MIN 93851136
#define O_W1P   93851136           // 4160*56 bf16 (padded W1)
#define NEED_FULL 94317056

#define N_IH  28953600
#define N_HH  16147200
#define N_W2  1781760

// legacy fp32-path offsets (float units) for fallback kernel
#define WS_L1  0
#define WS_H0  4160
#define WS_H1  6480
#define WS_L2  8800
#define WS_V   9568
#define WS_C   12640

typedef __attribute__((ext_vector_type(8))) short bf16x8;
typedef __attribute__((ext_vector_type(4))) float f32x4;

__device__ __forceinline__ float wred(float v) {
#pragma unroll
  for (int m = 32; m; m >>= 1) v += __shfl_xor(v, m, 64);
  return v;
}
__device__ __forceinline__ float dot4(float4 a, float4 b) {
  return a.x * b.x + a.y * b.y + a.z * b.z + a.w * b.w;
}
__device__ __forceinline__ float blo(unsigned u) {
  unsigned t = u << 16; return __builtin_bit_cast(float, t);
}
__device__ __forceinline__ float bhi(unsigned u) {
  unsigned t = u & 0xFFFF0000u; return __builtin_bit_cast(float, t);
}
__device__ __forceinline__ float dot8bb(uint4 w, uint4 x) {
  float s;
  s  = blo(w.x) * blo(x.x) + bhi(w.x) * bhi(x.x);
  s += blo(w.y) * blo(x.y) + bhi(w.y) * bhi(x.y);
  s += blo(w.z) * blo(x.z) + bhi(w.z) * bhi(x.z);
  s += blo(w.w) * blo(x.w) + bhi(w.w) * bhi(x.w);
  return s;
}
__device__ __forceinline__ unsigned short f2bf(float f) {  // RNE
  unsigned u = __builtin_bit_cast(unsigned, f);
  unsigned r = u + 0x7FFF + ((u >> 16) & 1);
  return (unsigned short)(r >> 16);
}

// ---- scoped accessors: cross-block data goes through the coherence point,
// ---- with NO cache-invalidating acquire fences anywhere.
__device__ __forceinline__ void st_ag_f32(float* p, float v) {
  __hip_atomic_store(p, v, __ATOMIC_RELAXED, __HIP_MEMORY_SCOPE_AGENT);
}
__device__ __forceinline__ float ld_ag_f32(const float* p) {
  return __hip_atomic_load(p, __ATOMIC_RELAXED, __HIP_MEMORY_SCOPE_AGENT);
}
__device__ __forceinline__ void st_ag_u32(unsigned* p, unsigned v) {
  __hip_atomic_store(p, v, __ATOMIC_RELAXED, __HIP_MEMORY_SCOPE_AGENT);
}
__device__ __forceinline__ unsigned long long ld_ag_u64(const unsigned long long* p) {
  return __hip_atomic_load(p, __ATOMIC_RELAXED, __HIP_MEMORY_SCOPE_AGENT);
}

// ---------- two-level grid barrier: release-arrive, RELAXED polls,
// ---------- no threadfence, no acquire => zero cache invalidates ----------
__device__ __forceinline__ void gbar(unsigned* bar, int bid, unsigned target) {
  __syncthreads();
  if (threadIdx.x == 0) {
    unsigned* grp   = bar + (bid & 7);
    unsigned* lead  = bar + 8;
    unsigned* epoch = bar + 9;
    unsigned old = __hip_atomic_fetch_add(grp, 1u, __ATOMIC_RELEASE, __HIP_MEMORY_SCOPE_AGENT);
    if (old == 31u) {
      __hip_atomic_store(grp, 0u, __ATOMIC_RELAXED, __HIP_MEMORY_SCOPE_AGENT);
      unsigned lo = __hip_atomic_fetch_add(lead, 1u, __ATOMIC_ACQ_REL, __HIP_MEMORY_SCOPE_AGENT);
      if (lo == 7u) {
        __hip_atomic_store(lead, 0u, __ATOMIC_RELAXED, __HIP_MEMORY_SCOPE_AGENT);
        __hip_atomic_store(epoch, target, __ATOMIC_RELEASE, __HIP_MEMORY_SCOPE_AGENT);
      } else {
        while (__hip_atomic_load(epoch, __ATOMIC_RELAXED, __HIP_MEMORY_SCOPE_AGENT) < target)
          __builtin_amdgcn_s_sleep(1);
      }
    } else {
      while (__hip_atomic_load(epoch, __ATOMIC_RELAXED, __HIP_MEMORY_SCOPE_AGENT) < target)
        __builtin_amdgcn_s_sleep(1);
    }
  }
  __syncthreads();   // block-wide hw+compiler barrier: orders all later loads
}

// ---------------- pre-pass conversion kernels ----------------
__global__ __launch_bounds__(256) void k_cvt(const float4* __restrict__ src,
                                             ushort4* __restrict__ dst, int n4) {
  int i = blockIdx.x * 256 + threadIdx.x, st = gridDim.x * 256;
  for (; i < n4; i += st) {
    float4 v = src[i];
    ushort4 o;
    o.x = f2bf(v.x); o.y = f2bf(v.y); o.z = f2bf(v.z); o.w = f2bf(v.w);
    dst[i] = o;
  }
}
__global__ __launch_bounds__(256) void k_cvtw1(const float* __restrict__ W1,
                                               unsigned short* __restrict__ dst) {
  int i = blockIdx.x * 256 + threadIdx.x;           // over 4160*56
  if (i < 4160 * 56) {
    int r = i / 56, c = i - r * 56;
    dst[i] = (c < 52) ? f2bf(W1[r * 52 + c]) : (unsigned short)0;
  }
}
__global__ __launch_bounds__(256) void k_h0(const float* __restrict__ h0,
                                            unsigned short* __restrict__ hb0,
                                            unsigned short* __restrict__ hb1) {
  int j = blockIdx.x * 256 + threadIdx.x;
  if (j < 2336) {
    hb1[j] = (j < 2320) ? f2bf(h0[j]) : (unsigned short)0;
    if (j >= 2320) hb0[j] = 0;
  }
}

// ================= main 2-sync kernel (scoped communication) =================
__global__ __launch_bounds__(1024, 4) void knet2(
    const float* __restrict__ y_seq, const float* __restrict__ x0,
    const float* __restrict__ h0, const float* __restrict__ A,
    const float* __restrict__ Cm, const float* __restrict__ W1,
    const float* __restrict__ b1, const float* __restrict__ b_ih,
    const float* __restrict__ b_hh, const float* __restrict__ b2,
    const float* __restrict__ W3, const float* __restrict__ b3,
    float* __restrict__ out, char* __restrict__ wsb, int use_w1p)
{
  const int tid  = threadIdx.x;
  const int lane = tid & 63;
  const int wav  = tid >> 6;
  const int bid  = blockIdx.x;

  unsigned* bar = (unsigned*)(wsb + O_BAR);
  float* zp  = (float*)(wsb + O_ZP);
  float* gi  = (float*)(wsb + O_GI);
  float* gh  = (float*)(wsb + O_GH);
  const unsigned short* bwih = (const unsigned short*)(wsb + O_WIH);
  const unsigned short* bwhh = (const unsigned short*)(wsb + O_WHH);
  const unsigned short* bw2  = (const unsigned short*)(wsb + O_W2B);
  const uint4* w1p = (const uint4*)(wsb + O_W1P);

  __shared__ __align__(16) uint4 s_l1u[520];     // l1 bf16 (B')
  __shared__ __align__(16) uint4 s_h4u[292];     // h bf16 (B' MFMA operand)
  __shared__ __align__(16) unsigned short s_h2[2336];  // h_new bf16 (C)
  __shared__ float s_part[4][4][16];
  __shared__ __align__(16) unsigned short s_kgb[64];
  __shared__ __align__(16) float s_kgf[52];
  __shared__ float s_innov[48];
  __shared__ float s_a[192];
  __shared__ float s_l2loc[8];
  __shared__ float s_xpost[4], s_xprior[4], s_dx[4];
  __shared__ float s_sc2, s_sc4;

  unsigned ep = 0;

  for (int t = 0; t <= T_STEPS; ++t) {
    // ======== B' prologue: x_post(t) from z-partials(t-1) [all blocks] ========
    if (t == 0) {
      if (tid < 4) s_xpost[tid] = x0[tid];
    } else {
      if (tid < 4) {
        float z = 0.f;
        for (int p = 0; p < 96; ++p) z += ld_ag_f32(&zp[p * 4 + tid]);
        float cb = 0.f;
        for (int j = 0; j < 48; ++j) cb += s_innov[j] * b3[tid * 48 + j];
        float xn = s_xprior[tid] + (z + cb) * 1e-4f;
        s_xpost[tid] = xn;
        if (bid == 0) out[tid * T_STEPS + (t - 1)] = xn;
      }
    }
    __syncthreads();
    if (t == T_STEPS) return;

    // ======== B' small math: x_prior, innov, kg_in ========
    if (tid < 4) {
      float xpr = 0.f;
#pragma unroll
      for (int j = 0; j < 4; j++) xpr += A[tid * 4 + j] * s_xpost[j];
      s_xprior[tid] = xpr;
    }
    __syncthreads();
    if (tid < 48) {
      float yp = Cm[tid * 5 + 4];
#pragma unroll
      for (int j = 0; j < 4; j++) yp += Cm[tid * 5 + j] * s_xprior[j];
      s_innov[tid] = y_seq[tid * T_STEPS + t] - yp;
    }
    if (tid >= 64 && tid < 68) {
      int i = tid - 64;
      s_dx[i] = s_xpost[i] - s_xprior[i];
    }
    __syncthreads();
    if (tid == 0) {
      float s2 = 0.f;
      for (int r = 0; r < 48; r++) s2 += s_innov[r] * s_innov[r];
      s_sc2 = 1.0f / fmaxf(sqrtf(s2), 1e-12f);
      float s4 = 0.f;
      for (int i = 0; i < 4; i++) s4 += s_dx[i] * s_dx[i];
      s_sc4 = 1.0f / fmaxf(sqrtf(s4), 1e-12f);
    }
    __syncthreads();
    if (tid < 64) {
      float v = (tid < 48) ? s_innov[tid] * s_sc2
              : (tid < 52) ? s_dx[tid - 48] * s_sc4 : 0.f;
      s_kgb[tid] = f2bf(v);
      if (tid < 52) s_kgf[tid] = v;
    }
    // stage h(t-1) bf16 into LDS via agent loads (h changes every step)
    {
      const unsigned long long* hbg =
          (const unsigned long long*)(wsb + O_HB + ((t + 1) & 1) * HB_STR);
      unsigned long long* dst = (unsigned long long*)s_h4u;
      if (tid < 584) dst[tid] = ld_ag_u64(hbg + tid);
    }
    __syncthreads();

    // ======== B' l1 = relu(W1 @ kg + b1), redundant per block ========
    if (use_w1p) {
      const uint4* kg4 = (const uint4*)s_kgb;
      for (int r = tid; r < 4160; r += 1024) {
        const uint4* wr = w1p + (size_t)r * 7;
        float acc = b1[r];
#pragma unroll
        for (int c = 0; c < 7; c++) acc += dot8bb(wr[c], kg4[c]);
        ((unsigned short*)s_l1u)[r] = f2bf(fmaxf(acc, 0.f));
      }
    } else {
      const float4* kg4 = (const float4*)s_kgf;
      for (int r = tid; r < 4160; r += 1024) {
        const float4* wr = (const float4*)(W1 + (size_t)r * 52);
        float acc = b1[r];
#pragma unroll
        for (int c = 0; c < 13; c++) acc += dot4(wr[c], kg4[c]);
        ((unsigned short*)s_l1u)[r] = f2bf(fmaxf(acc, 0.f));
      }
    }
    __syncthreads();

    // ======== B' GRU GEMV via MFMA, 8-deep prefetch (normal cached loads) ========
    {
      const int q  = wav >> 2;        // job slot 0..3
      const int kw = wav & 3;         // k-split
      const int job = bid + 256 * q;
      if (job < 870) {
        const int side = (job < 435) ? 0 : 1;
        const int rt   = side ? (job - 435) : job;
        const int row  = rt * 16 + (lane & 15);
        const int xoff = lane >> 4;
        const uint4* xs;
        const uint4* wp;
        int kbeg, kend;
        if (side == 0) {
          xs = s_l1u;
          wp = (const uint4*)(bwih + (size_t)row * 4160) + xoff;
          kbeg = kw * 33; kend = kbeg + 33; if (kend > 130) kend = 130;
        } else {
          xs = s_h4u;
          wp = (const uint4*)(bwhh + (size_t)row * 2320) + xoff;
          kbeg = kw * 19; kend = kbeg + 19; if (kend > 73) kend = 73;
        }
        f32x4 acc = {0.f, 0.f, 0.f, 0.f};
        uint4 b0 = wp[(size_t)(kbeg + 0) * 4];
        uint4 b1r = wp[(size_t)(kbeg + 1) * 4];
        uint4 b2r = wp[(size_t)(kbeg + 2) * 4];
        uint4 b3r = wp[(size_t)(kbeg + 3) * 4];
        uint4 b4 = wp[(size_t)(kbeg + 4) * 4];
        uint4 b5 = wp[(size_t)(kbeg + 5) * 4];
        uint4 b6 = wp[(size_t)(kbeg + 6) * 4];
        uint4 b7 = wp[(size_t)(kbeg + 7) * 4];
        int kt = kbeg;
#define GSTEP(P, B) { acc = __builtin_amdgcn_mfma_f32_16x16x32_bf16( \
            __builtin_bit_cast(bf16x8, B), \
            __builtin_bit_cast(bf16x8, xs[(kt + P) * 4 + xoff]), acc, 0, 0, 0); \
            B = wp[(size_t)(kt + 8 + P) * 4]; }
        while (kt + 8 <= kend) {
          GSTEP(0, b0) GSTEP(1, b1r) GSTEP(2, b2r) GSTEP(3, b3r)
          GSTEP(4, b4) GSTEP(5, b5) GSTEP(6, b6) GSTEP(7, b7)
          kt += 8;
        }
#undef GSTEP
#define TSTEP(P, B) if (kt + P < kend) acc = __builtin_amdgcn_mfma_f32_16x16x32_bf16( \
            __builtin_bit_cast(bf16x8, B), \
            __builtin_bit_cast(bf16x8, xs[(kt + P) * 4 + xoff]), acc, 0, 0, 0);
        TSTEP(0, b0) TSTEP(1, b1r) TSTEP(2, b2r) TSTEP(3, b3r)
        TSTEP(4, b4) TSTEP(5, b5) TSTEP(6, b6) TSTEP(7, b7)
#undef TSTEP
        if ((lane & 15) == 0) {
          int rb = (lane >> 4) * 4;
#pragma unroll
          for (int i = 0; i < 4; i++) s_part[q][kw][rb + i] = acc[i];
        }
      }
    }
    __syncthreads();
    if (tid < 64) {
      int q = tid >> 4, r = tid & 15;
      int job = bid + 256 * q;
      if (job < 870) {
        float s = s_part[q][0][r] + s_part[q][1][r] + s_part[q][2][r] + s_part[q][3][r];
        if (job < 435) st_ag_f32(&gi[job * 16 + r], s);
        else st_ag_f32(&gh[(job - 435) * 16 + r], s);
      }
    }
    ++ep; gbar(bar, bid, ep);   // -------- SYNC 1: gi/gh ready --------

    // ======== C: gates (96 blocks, redundant), l2, z-partials ========
    if (bid < 96) {
      float* hf_out = (float*)(wsb + O_HF + (t & 1) * HF_STR);
      unsigned* hb_out32 = (unsigned*)(wsb + O_HB + (t & 1) * HB_STR);
      const float* hf_old = (const float*)(wsb + O_HF + ((t + 1) & 1) * HF_STR);
      for (int j = tid; j < 2320; j += 1024) {
        float ir = ld_ag_f32(&gi[j]) + b_ih[j];
        float iz = ld_ag_f32(&gi[2320 + j]) + b_ih[2320 + j];
        float ig = ld_ag_f32(&gi[4640 + j]) + b_ih[4640 + j];
        float hr = ld_ag_f32(&gh[j]) + b_hh[j];
        float hz = ld_ag_f32(&gh[2320 + j]) + b_hh[2320 + j];
        float hg = ld_ag_f32(&gh[4640 + j]) + b_hh[4640 + j];
        float rr = 1.f / (1.f + expf(-(ir + hr)));
        float zz = 1.f / (1.f + expf(-(iz + hz)));
        float gg = tanhf(ig + rr * hg);
        float hold = (t == 0) ? h0[j] : ld_ag_f32(&hf_old[j]);
        float hn = (1.f - zz) * gg + zz * hold;
        s_h2[j] = f2bf(hn);
        if (bid == 0) st_ag_f32(&hf_out[j], hn);
      }
      if (tid < 16) s_h2[2320 + tid] = 0;   // keep K-pad zero
      __syncthreads();
      // publish h_new bf16 (bid 0 only), packed u32 agent stores
      if (bid == 0 && tid < 1168) {
        unsigned v = (unsigned)s_h2[2 * tid] | ((unsigned)s_h2[2 * tid + 1] << 16);
        st_ag_u32(hb_out32 + tid, v);
      }
      // l2 rows (8 per block), bf16 VALU dot from LDS (normal cached W2)
      if (wav < 8) {
        const int row = bid * 8 + wav;
        const uint4* wr = (const uint4*)(bw2 + (size_t)row * 2320);
        const uint4* hx = (const uint4*)s_h2;
        float acc = 0.f;
        for (int k = lane; k < 290; k += 64) acc += dot8bb(wr[k], hx[k]);
        acc = wred(acc);
        if (lane == 0) s_l2loc[wav] = fmaxf(acc + b2[row], 0.f);
      }
      __syncthreads();
      // z-partials
      if (tid < 192) {
        const float* w3r = W3 + (size_t)tid * 768 + bid * 8;
        float a = 0.f;
#pragma unroll
        for (int r = 0; r < 8; r++) a += w3r[r] * s_l2loc[r];
        s_a[tid] = a * s_innov[tid % 48];
      }
      __syncthreads();
      if (tid < 4) {
        float zv = 0.f;
        for (int j = 0; j < 48; j++) zv += s_a[tid * 48 + j];
        st_ag_f32(&zp[bid * 4 + tid], zv);
      }
    }
    ++ep; gbar(bar, bid, ep);   // -------- SYNC 2: h/l2/z ready --------
  }
}

// ================= cooperative fp32 kernel (proven fallback) =================
__global__ __launch_bounds__(256, 2) void knet(
    const float* __restrict__ y_seq, const float* __restrict__ x0,
    const float* __restrict__ h0, const float* __restrict__ A,
    const float* __restrict__ Cm, const float* __restrict__ W1,
    const float* __restrict__ b1, const float* __restrict__ W_ih,
    const float* __restrict__ W_hh, const float* __restrict__ b_ih,
    const float* __restrict__ b_hh, const float* __restrict__ W2,
    const float* __restrict__ b2, const float* __restrict__ W3,
    const float* __restrict__ b3, float* __restrict__ out,
    float* __restrict__ ws)
{
  cg::grid_group grid = cg::this_grid();
  const int tid = threadIdx.x, lane = tid & 63, wav = tid >> 6, bid = blockIdx.x;
  const int gt = bid * 256 + tid, wave_g = bid * 4 + wav, NW = gridDim.x * 4;

  __shared__ __align__(16) float4 s_buf4[1040];
  __shared__ __align__(16) float4 s_h4[580];
  __shared__ __align__(16) float s_kgin[52];
  __shared__ float s_innov[48];
  __shared__ float s_xpost[4], s_xprior[4], s_dx[4];
  __shared__ float s_sc2, s_sc4;

  for (int t = 0; t <= T_STEPS; ++t) {
    if (t == 0) {
      if (tid < 4) s_xpost[tid] = x0[tid];
    } else {
      const float4* vv  = (const float4*)(ws + WS_V + wav * 768);
      const float4* l2v = (const float4*)(ws + WS_L2);
      float acc = 0.f;
      for (int k = lane; k < 192; k += 64) acc += dot4(vv[k], l2v[k]);
      acc = wred(acc);
      if (lane == 0)
        s_xpost[wav] = s_xprior[wav] + (acc + ws[WS_C + wav]) * 1e-4f;
    }
    __syncthreads();
    if (bid == 0 && t > 0 && tid < 4) out[tid * T_STEPS + (t - 1)] = s_xpost[tid];
    if (t == T_STEPS) return;

    if (tid < 4) {
      float xp = 0.f;
#pragma unroll
      for (int j = 0; j < 4; j++) xp += A[tid * 4 + j] * s_xpost[j];
      s_xprior[tid] = xp;
    }
    __syncthreads();
    if (tid < 48) {
      float yp = Cm[tid * 5 + 4];
#pragma unroll
      for (int j = 0; j < 4; j++) yp += Cm[tid * 5 + j] * s_xprior[j];
      s_innov[tid] = y_seq[tid * T_STEPS + t] - yp;
    }
    if (tid >= 64 && tid < 68) {
      int i = tid - 64;
      s_dx[i] = s_xpost[i] - s_xprior[i];
    }
    __syncthreads();
    if (tid == 0) {
      float s2 = 0.f;
      for (int r = 0; r < 48; r++) s2 += s_innov[r] * s_innov[r];
      s_sc2 = 1.0f / fmaxf(sqrtf(s2), 1e-12f);
      float s4 = 0.f;
      for (int i = 0; i < 4; i++) s4 += s_dx[i] * s_dx[i];
      s_sc4 = 1.0f / fmaxf(sqrtf(s4), 1e-12f);
    }
    __syncthreads();
    if (tid < 48) s_kgin[tid] = s_innov[tid] * s_sc2;
    else if (tid < 52) s_kgin[tid] = s_dx[tid - 48] * s_sc4;
    __syncthreads();

    if (gt < 4160) {
      const float4* wr  = (const float4*)(W1 + (size_t)gt * 52);
      const float4* kg4 = (const float4*)s_kgin;
      float acc = b1[gt];
#pragma unroll
      for (int k = 0; k < 13; k++) acc += dot4(wr[k], kg4[k]);
      ws[WS_L1 + gt] = fmaxf(acc, 0.f);
    }
    grid.sync();

    {
      const float* h_old = (t == 0) ? h0 : (ws + (((t & 1) == 0) ? WS_H0 : WS_H1));
      float* h_new = ws + (((t & 1) == 0) ? WS_H1 : WS_H0);
      const float4* l1g = (const float4*)(ws + WS_L1);
      for (int i = tid; i < 1040; i += 256) s_buf4[i] = l1g[i];
      const float4* hog = (const float4*)h_old;
      for (int i = tid; i < 580; i += 256) s_h4[i] = hog[i];
      __syncthreads();
      const float* s_h = (const float*)s_h4;

      for (int j = wave_g; j < 2320; j += NW) {
        const float4* r0 = (const float4*)(W_ih + (size_t)j * 4160);
        const float4* r1 = (const float4*)(W_ih + (size_t)(j + 2320) * 4160);
        const float4* r2 = (const float4*)(W_ih + (size_t)(j + 4640) * 4160);
        float a0 = 0.f, a1 = 0.f, a2 = 0.f;
#pragma unroll 4
        for (int k = lane; k < 1040; k += 64) {
          float4 x = s_buf4[k];
          a0 += dot4(r0[k], x); a1 += dot4(r1[k], x); a2 += dot4(r2[k], x);
        }
        const float4* q0 = (const float4*)(W_hh + (size_t)j * 2320);
        const float4* q1 = (const float4*)(W_hh + (size_t)(j + 2320) * 2320);
        const float4* q2 = (const float4*)(W_hh + (size_t)(j + 4640) * 2320);
        float c0 = 0.f, c1 = 0.f, c2 = 0.f;
#pragma unroll 4
        for (int k = lane; k < 580; k += 64) {
          float4 x = s_h4[k];
          c0 += dot4(q0[k], x); c1 += dot4(q1[k], x); c2 += dot4(q2[k], x);
        }
        a0 = wred(a0); a1 = wred(a1); a2 = wred(a2);
        c0 = wred(c0); c1 = wred(c1); c2 = wred(c2);
        if (lane == 0) {
          float ir = a0 + b_ih[j], iz = a1 + b_ih[j + 2320], ig = a2 + b_ih[j + 4640];
          float hr = c0 + b_hh[j], hz = c1 + b_hh[j + 2320], hg = c2 + b_hh[j + 4640];
          float rr = 1.f / (1.f + expf(-(ir + hr)));
          float zz = 1.f / (1.f + expf(-(iz + hz)));
          float gg = tanhf(ig + rr * hg);
          h_new[j] = (1.f - zz) * gg + zz * s_h[j];
        }
      }
    }
    grid.sync();

    {
      const float* h_new = ws + (((t & 1) == 0) ? WS_H1 : WS_H0);
      const float4* hv = (const float4*)h_new;
      for (int i = tid; i < 580; i += 256) s_buf4[i] = hv[i];
      __syncthreads();

      if (gt < 3072) {
        int i = gt / 768, cc = gt - i * 768;
        const float* wcol = W3 + (size_t)(i * 48) * 768 + cc;
        float acc = 0.f;
#pragma unroll 8
        for (int j = 0; j < 48; j++) acc += s_innov[j] * wcol[(size_t)j * 768];
        ws[WS_V + gt] = acc;
      } else if (gt < 3076) {
        int i = gt - 3072;
        float acc = 0.f;
        for (int j = 0; j < 48; j++) acc += s_innov[j] * b3[i * 48 + j];
        ws[WS_C + i] = acc;
      }

      for (int task = wave_g; task < 768; task += NW) {
        const float4* row = (const float4*)(W2 + (size_t)task * 2320);
        float acc = 0.f;
#pragma unroll 4
        for (int k = lane; k < 580; k += 64) acc += dot4(row[k], s_buf4[k]);
        acc = wred(acc);
        if (lane == 0) ws[WS_L2 + task] = fmaxf(acc + b2[task], 0.f);
      }
    }
    grid.sync();
  }
}

extern "C" void kernel_launch(void* const* d_in, const int* in_sizes, int n_in,
                              void* d_out, int out_size, void* d_ws, size_t ws_size,
                              hipStream_t stream) {
  const float* y_seq = (const float*)d_in[0];
  const float* x0    = (const float*)d_in[1];
  const float* h0    = (const float*)d_in[2];
  const float* A     = (const float*)d_in[3];
  const float* Cm    = (const float*)d_in[4];
  const float* W1    = (const float*)d_in[5];
  const float* b1    = (const float*)d_in[6];
  const float* W_ih  = (const float*)d_in[7];
  const float* W_hh  = (const float*)d_in[8];
  const float* b_ih  = (const float*)d_in[9];
  const float* b_hh  = (const float*)d_in[10];
  const float* W2    = (const float*)d_in[11];
  const float* b2    = (const float*)d_in[12];
  const float* W3    = (const float*)d_in[13];
  const float* b3    = (const float*)d_in[14];
  float* out = (float*)d_out;
  float* ws  = (float*)d_ws;
  char* wsb  = (char*)d_ws;

  if (ws_size >= NEED_MIN) {
    int use_w1p = (ws_size >= NEED_FULL) ? 1 : 0;
    hipMemsetAsync(wsb + O_BAR, 0, 256, stream);
    k_cvt<<<1024, 256, 0, stream>>>((const float4*)W_ih,
                                    (ushort4*)(wsb + O_WIH), N_IH / 4);
    k_cvt<<<1024, 256, 0, stream>>>((const float4*)W_hh,
                                    (ushort4*)(wsb + O_WHH), N_HH / 4);
    k_cvt<<<512, 256, 0, stream>>>((const float4*)W2,
                                   (ushort4*)(wsb + O_W2B), N_W2 / 4);
    if (use_w1p)
      k_cvtw1<<<(4160 * 56 + 255) / 256, 256, 0, stream>>>(
          W1, (unsigned short*)(wsb + O_W1P));
    k_h0<<<10, 256, 0, stream>>>(h0, (unsigned short*)(wsb + O_HB),
                                 (unsigned short*)(wsb + O_HB + HB_STR));

    void* args[] = { &y_seq, &x0, &h0, &A, &Cm, &W1, &b1, &b_ih, &b_hh,
                     &b2, &W3, &b3, &out, &wsb, &use_w1p };
    hipError_t err = hipLaunchCooperativeKernel(
        reinterpret_cast<void*>(knet2), dim3(256), dim3(1024), args, 0, stream);
    if (err == hipSuccess) return;
  }

  {
    int nb = 0;
    hipError_t oe = hipOccupancyMaxActiveBlocksPerMultiprocessor(
        &nb, (const void*)knet, 256, 0);
    int bpc = (oe == hipSuccess && nb >= 1) ? (nb > 1 ? 1 : nb) : 1;
    void* args[] = { &y_seq, &x0, &h0, &A, &Cm, &W1, &b1, &W_ih, &W_hh,
                     &b_ih, &b_hh, &W2, &b2, &W3, &b3, &out, &ws };
    hipLaunchCooperativeKernel(
        reinterpret_cast<void*>(knet), dim3(256 * bpc), dim3(256), args, 0, stream);
  }
}